// Round 19
// baseline (166.281 us; speedup 1.0000x reference)
//
#include <hip/hip_runtime.h>
#include <hip/hip_bf16.h>

#define DMODEL 1024
#define NHEAD  16
#define DHEAD  64
#define BB     4
#define MM     1024
#define NN     2048
#define LOG2E  1.4426950408889634f

typedef __attribute__((ext_vector_type(8))) short bf16x8;
typedef __attribute__((ext_vector_type(4))) float f32x4;

#define AS1 __attribute__((address_space(1)))
#define AS3 __attribute__((address_space(3)))

__device__ __forceinline__ unsigned short f2bf(float f) {
  unsigned int u = __builtin_bit_cast(unsigned int, f);
  unsigned int r = (u + 0x7fffu + ((u >> 16) & 1u)) >> 16;
  return (unsigned short)r;
}
__device__ __forceinline__ float bf2f(unsigned int u16) {
  return __builtin_bit_cast(float, u16 << 16);
}

// ---------------------------------------------------------------- fused cast f32 -> bf16
__global__ __launch_bounds__(256)
void cast_all(const float* __restrict__ Q, const float* __restrict__ KV,
              const float* __restrict__ W0, const float* __restrict__ W1,
              const float* __restrict__ W2, const float* __restrict__ W3,
              unsigned short* __restrict__ oQ, unsigned short* __restrict__ oKV,
              unsigned short* __restrict__ o0, unsigned short* __restrict__ o1,
              unsigned short* __restrict__ o2, unsigned short* __restrict__ o3)
{
  const int bid = blockIdx.x;
  const float* s; unsigned short* d; int i;
  if (bid < 4096)       { s = Q;  d = oQ;  i = bid * 256 + threadIdx.x; }
  else if (bid < 12288) { s = KV; d = oKV; i = (bid - 4096) * 256 + threadIdx.x; }
  else {
    const int w = (bid - 12288) >> 10;
    s = w == 0 ? W0 : w == 1 ? W1 : w == 2 ? W2 : W3;
    d = w == 0 ? o0 : w == 1 ? o1 : w == 2 ? o2 : o3;
    i = ((bid - 12288) & 1023) * 256 + threadIdx.x;
  }
  const float4 v = ((const float4*)s)[i];
  union { unsigned short us[4]; unsigned long long u64; } o;
  o.us[0] = f2bf(v.x); o.us[1] = f2bf(v.y); o.us[2] = f2bf(v.z); o.us[3] = f2bf(v.w);
  *(unsigned long long*)(d + (size_t)i * 4) = o.u64;
}

// ---------------------------------------------------------------- fused QKV GEMM
// grid 768:  [0,256)  q-proj  : R13 single-barrier ring-3 path (unchanged)
//            [256,768) merged k+v : one A-stage feeds BOTH k and v (32 MFMA/step,
//                      2-barrier ring-2 dbuf, 6 loads/step, same 48KB LDS)
__global__ __launch_bounds__(256)
void qkv_gemm(const unsigned short* __restrict__ Qbf,
              const unsigned short* __restrict__ KVbf,
              const unsigned short* __restrict__ Wqb,
              const unsigned short* __restrict__ Wkb,
              const unsigned short* __restrict__ Wvb,
              const float* __restrict__ bq, const float* __restrict__ bk,
              const float* __restrict__ bv,
              unsigned short* __restrict__ qout,
              unsigned short* __restrict__ kout,
              unsigned short* __restrict__ vtout)
{
  __shared__ unsigned short lds[24576];   // 48 KB, aliased per path

  const int bid = blockIdx.x;
  const int tid  = threadIdx.x;
  const int wave = tid >> 6;
  const int lane = tid & 63;
  const int l15  = lane & 15;
  const int l4   = lane >> 4;
  const int wm   = wave >> 1;
  const int wn   = wave & 1;

  const int cc0 = (wave * 2) * 64 + lane;
  const int cc1 = cc0 + 64;
  const int r0 = cc0 >> 2, sch0 = (cc0 & 3) ^ (r0 & 3);
  const int r1 = cc1 >> 2, sch1 = (cc1 & 3) ^ (r1 & 3);

  if (bid < 256) {
    // ---------------- q-proj path (R13 proven, ring-3 single-barrier) ----------------
    const int xcd = bid & 7;
    const int l   = bid >> 3;
    const int mb  = xcd * 4 + (l >> 3);
    const int nb  = l & 7;
    const size_t row0 = (size_t)mb * 128;
    const size_t col0 = (size_t)nb * 128;

    unsigned short* As = lds;            // 3 x 4096
    unsigned short* Ws = lds + 12288;    // 3 x 4096

    f32x4 acc[4][4] = {};

    const unsigned short* ap0 = Qbf + (row0 + r0) * DMODEL + sch0 * 8;
    const unsigned short* ap1 = Qbf + (row0 + r1) * DMODEL + sch1 * 8;
    const unsigned short* wp0 = Wqb + (col0 + r0) * DMODEL + sch0 * 8;
    const unsigned short* wp1 = Wqb + (col0 + r1) * DMODEL + sch1 * 8;

    auto stage = [&](int buf) {
      __builtin_amdgcn_global_load_lds((const AS1 void*)ap0, (AS3 void*)(&As[buf * 4096 + cc0 * 8]), 16, 0, 0);
      __builtin_amdgcn_global_load_lds((const AS1 void*)ap1, (AS3 void*)(&As[buf * 4096 + cc1 * 8]), 16, 0, 0);
      __builtin_amdgcn_global_load_lds((const AS1 void*)wp0, (AS3 void*)(&Ws[buf * 4096 + cc0 * 8]), 16, 0, 0);
      __builtin_amdgcn_global_load_lds((const AS1 void*)wp1, (AS3 void*)(&Ws[buf * 4096 + cc1 * 8]), 16, 0, 0);
      ap0 += 32; ap1 += 32; wp0 += 32; wp1 += 32;
    };

    stage(0);
    stage(1);

    int cur = 0;
    for (int kt = 0; kt < 32; ++kt) {
      if (kt < 31) asm volatile("s_waitcnt vmcnt(4)" ::: "memory");
      else         asm volatile("s_waitcnt vmcnt(0)" ::: "memory");
      __builtin_amdgcn_sched_barrier(0);
      __builtin_amdgcn_s_barrier();
      __builtin_amdgcn_sched_barrier(0);
      if (kt < 30) {
        int nxt = cur + 2; if (nxt >= 3) nxt -= 3;
        stage(nxt);
      }

      bf16x8 af[4], bfr[4];
#pragma unroll
      for (int mi = 0; mi < 4; ++mi) {
        int r = wm * 64 + mi * 16 + l15;
        af[mi] = *(const bf16x8*)&As[cur * 4096 + r * 32 + ((l4 ^ (r & 3)) << 3)];
      }
#pragma unroll
      for (int ni = 0; ni < 4; ++ni) {
        int r = wn * 64 + ni * 16 + l15;
        bfr[ni] = *(const bf16x8*)&Ws[cur * 4096 + r * 32 + ((l4 ^ (r & 3)) << 3)];
      }
      __builtin_amdgcn_s_setprio(1);
#pragma unroll
      for (int mi = 0; mi < 4; ++mi)
#pragma unroll
        for (int ni = 0; ni < 4; ++ni)
          acc[mi][ni] = __builtin_amdgcn_mfma_f32_16x16x32_bf16(af[mi], bfr[ni], acc[mi][ni], 0, 0, 0);
      __builtin_amdgcn_s_setprio(0);

      cur = (cur == 2) ? 0 : cur + 1;
    }

#pragma unroll
    for (int mi = 0; mi < 4; ++mi) {
#pragma unroll
      for (int ni = 0; ni < 4; ++ni) {
        const int col = (int)col0 + wn * 64 + ni * 16 + l15;
        const float bcol = bq[col];
#pragma unroll
        for (int i = 0; i < 4; ++i) {
          const size_t row = row0 + wm * 64 + mi * 16 + l4 * 4 + i;
          const float v = (acc[mi][ni][i] + bcol) * (0.125f * LOG2E);
          qout[row * DMODEL + col] = __builtin_bit_cast(unsigned short, __float2bfloat16(v));
        }
      }
    }
  } else {
    // ---------------- merged k+v path (2-barrier ring-2 dbuf, 32 MFMA/step) ----------
    const int lb2 = bid - 256;           // 0..511
    const int xcd = lb2 & 7;
    const int l   = lb2 >> 3;
    const int mb  = xcd * 8 + (l >> 3);  // 0..63
    const int nb  = l & 7;
    const size_t row0 = (size_t)mb * 128;
    const size_t col0 = (size_t)nb * 128;

    unsigned short* A2  = lds;           // 2 x 4096
    unsigned short* Wk2 = lds + 8192;    // 2 x 4096
    unsigned short* Wv2 = lds + 16384;   // 2 x 4096

    f32x4 acck[4][4] = {};
    f32x4 accv[4][4] = {};

    const unsigned short* ap0  = KVbf + (row0 + r0) * DMODEL + sch0 * 8;
    const unsigned short* ap1  = KVbf + (row0 + r1) * DMODEL + sch1 * 8;
    const unsigned short* wkp0 = Wkb + (col0 + r0) * DMODEL + sch0 * 8;
    const unsigned short* wkp1 = Wkb + (col0 + r1) * DMODEL + sch1 * 8;
    const unsigned short* wvp0 = Wvb + (col0 + r0) * DMODEL + sch0 * 8;
    const unsigned short* wvp1 = Wvb + (col0 + r1) * DMODEL + sch1 * 8;

    auto stage = [&](int buf) {
      __builtin_amdgcn_global_load_lds((const AS1 void*)ap0,  (AS3 void*)(&A2 [buf * 4096 + cc0 * 8]), 16, 0, 0);
      __builtin_amdgcn_global_load_lds((const AS1 void*)ap1,  (AS3 void*)(&A2 [buf * 4096 + cc1 * 8]), 16, 0, 0);
      __builtin_amdgcn_global_load_lds((const AS1 void*)wkp0, (AS3 void*)(&Wk2[buf * 4096 + cc0 * 8]), 16, 0, 0);
      __builtin_amdgcn_global_load_lds((const AS1 void*)wkp1, (AS3 void*)(&Wk2[buf * 4096 + cc1 * 8]), 16, 0, 0);
      __builtin_amdgcn_global_load_lds((const AS1 void*)wvp0, (AS3 void*)(&Wv2[buf * 4096 + cc0 * 8]), 16, 0, 0);
      __builtin_amdgcn_global_load_lds((const AS1 void*)wvp1, (AS3 void*)(&Wv2[buf * 4096 + cc1 * 8]), 16, 0, 0);
      ap0 += 32; ap1 += 32; wkp0 += 32; wkp1 += 32; wvp0 += 32; wvp1 += 32;
    };

    stage(0);

    for (int kt = 0; kt < 32; ++kt) {
      const int cur = kt & 1;
      if (kt < 31) {
        stage(cur ^ 1);
        asm volatile("s_waitcnt vmcnt(6)" ::: "memory");
      } else {
        asm volatile("s_waitcnt vmcnt(0)" ::: "memory");
      }
      __builtin_amdgcn_sched_barrier(0);
      __builtin_amdgcn_s_barrier();          // A: cur staged for all waves
      __builtin_amdgcn_sched_barrier(0);

      bf16x8 af[4], fr[4];
#pragma unroll
      for (int mi = 0; mi < 4; ++mi) {
        int r = wm * 64 + mi * 16 + l15;
        af[mi] = *(const bf16x8*)&A2[cur * 4096 + r * 32 + ((l4 ^ (r & 3)) << 3)];
      }
#pragma unroll
      for (int ni = 0; ni < 4; ++ni) {
        int r = wn * 64 + ni * 16 + l15;
        fr[ni] = *(const bf16x8*)&Wk2[cur * 4096 + r * 32 + ((l4 ^ (r & 3)) << 3)];
      }
      __builtin_amdgcn_s_setprio(1);
#pragma unroll
      for (int mi = 0; mi < 4; ++mi)
#pragma unroll
        for (int ni = 0; ni < 4; ++ni)
          acck[mi][ni] = __builtin_amdgcn_mfma_f32_16x16x32_bf16(af[mi], fr[ni], acck[mi][ni], 0, 0, 0);
      __builtin_amdgcn_s_setprio(0);

      // time-share frag regs: now read Wv (ds_read overlaps k-MFMA drain)
#pragma unroll
      for (int ni = 0; ni < 4; ++ni) {
        int r = wn * 64 + ni * 16 + l15;
        fr[ni] = *(const bf16x8*)&Wv2[cur * 4096 + r * 32 + ((l4 ^ (r & 3)) << 3)];
      }
      __builtin_amdgcn_s_setprio(1);
#pragma unroll
      for (int mi = 0; mi < 4; ++mi)
#pragma unroll
        for (int ni = 0; ni < 4; ++ni)
          accv[mi][ni] = __builtin_amdgcn_mfma_f32_16x16x32_bf16(af[mi], fr[ni], accv[mi][ni], 0, 0, 0);
      __builtin_amdgcn_s_setprio(0);

      asm volatile("s_waitcnt lgkmcnt(0)" ::: "memory");
      __builtin_amdgcn_sched_barrier(0);
      __builtin_amdgcn_s_barrier();          // B: reads done -> next stage may overwrite
      __builtin_amdgcn_sched_barrier(0);
    }

    // k epilogue
#pragma unroll
    for (int mi = 0; mi < 4; ++mi) {
#pragma unroll
      for (int ni = 0; ni < 4; ++ni) {
        const int col = (int)col0 + wn * 64 + ni * 16 + l15;
        const float bcol = bk[col];
#pragma unroll
        for (int i = 0; i < 4; ++i) {
          const size_t row = row0 + wm * 64 + mi * 16 + l4 * 4 + i;
          kout[row * DMODEL + col] = __builtin_bit_cast(unsigned short,
              __float2bfloat16(acck[mi][ni][i] + bcol));
        }
      }
    }
    // v epilogue -> V^T  vt[(b*16+h)][d][n]
#pragma unroll
    for (int mi = 0; mi < 4; ++mi) {
#pragma unroll
      for (int ni = 0; ni < 4; ++ni) {
        const int col = (int)col0 + wn * 64 + ni * 16 + l15;
        const float bcol = bv[col];
        const int row = (int)row0 + wm * 64 + mi * 16 + l4 * 4;
        const int b = row >> 11, n = row & 2047;
        const int h = col >> 6, d = col & 63;
        union { unsigned short us[4]; uint2 u; } pk;
#pragma unroll
        for (int i = 0; i < 4; ++i)
          pk.us[i] = __builtin_bit_cast(unsigned short, __float2bfloat16(accv[mi][ni][i] + bcol));
        *(uint2*)(vtout + (((size_t)(b * 16 + h) * 64 + d) << 11) + n) = pk.u;
      }
    }
  }
}

// ---------------------------------------------------------------- o-proj GEMM (64x128 tile)
// single-barrier ring-3 (36KB), stage-after-barrier, vmcnt(3).  bf16 resid/out.
__global__ __launch_bounds__(256)
void gemm_o(const unsigned short* __restrict__ A,
            const unsigned short* __restrict__ W,
            const float* __restrict__ bias,
            const unsigned short* __restrict__ resid,
            unsigned short* __restrict__ out)
{
  __shared__ unsigned short As[3][64 * 32];
  __shared__ unsigned short Ws[3][128 * 32];

  const int bid = blockIdx.x;
  const int xcd = bid & 7;
  const int l   = bid >> 3;
  const int mb  = xcd * 8 + (l >> 3);
  const int nb  = l & 7;

  const int tid  = threadIdx.x;
  const int wave = tid >> 6;
  const int lane = tid & 63;
  const int l15  = lane & 15;
  const int l4   = lane >> 4;
  const int wm   = wave >> 1;
  const int wn   = wave & 1;
  const size_t row0 = (size_t)mb * 64;
  const size_t col0 = (size_t)nb * 128;

  f32x4 acc[2][4] = {};

  const int ra = tid >> 2, scha = (tid & 3) ^ (ra & 3);
  const int cc0 = (wave * 2) * 64 + lane;
  const int cc1 = cc0 + 64;
  const int r0 = cc0 >> 2, sch0 = (cc0 & 3) ^ (r0 & 3);
  const int r1 = cc1 >> 2, sch1 = (cc1 & 3) ^ (r1 & 3);
  const unsigned short* ap  = A + (row0 + ra) * DMODEL + scha * 8;
  const unsigned short* wp0 = W + (col0 + r0) * DMODEL + sch0 * 8;
  const unsigned short* wp1 = W + (col0 + r1) * DMODEL + sch1 * 8;

  auto stage = [&](int buf) {
    __builtin_amdgcn_global_load_lds((const AS1 void*)ap,  (AS3 void*)(&As[buf][tid * 8]), 16, 0, 0);
    __builtin_amdgcn_global_load_lds((const AS1 void*)wp0, (AS3 void*)(&Ws[buf][cc0 * 8]), 16, 0, 0);
    __builtin_amdgcn_global_load_lds((const AS1 void*)wp1, (AS3 void*)(&Ws[buf][cc1 * 8]), 16, 0, 0);
    ap += 32; wp0 += 32; wp1 += 32;
  };

  stage(0);
  stage(1);

  int cur = 0;
  for (int kt = 0; kt < 32; ++kt) {
    if (kt < 31) {
      asm volatile("s_waitcnt vmcnt(3)" ::: "memory");
    } else {
      asm volatile("s_waitcnt vmcnt(0)" ::: "memory");
    }
    __builtin_amdgcn_sched_barrier(0);
    __builtin_amdgcn_s_barrier();
    __builtin_amdgcn_sched_barrier(0);
    if (kt < 30) {
      int nxt = cur + 2; if (nxt >= 3) nxt -= 3;
      stage(nxt);
    }

    bf16x8 af[2], bfr[4];
#pragma unroll
    for (int mi = 0; mi < 2; ++mi) {
      int r = wm * 32 + mi * 16 + l15;
      af[mi] = *(const bf16x8*)&As[cur][r * 32 + ((l4 ^ (r & 3)) << 3)];
    }
#pragma unroll
    for (int ni = 0; ni < 4; ++ni) {
      int r = wn * 64 + ni * 16 + l15;
      bfr[ni] = *(const bf16x8*)&Ws[cur][r * 32 + ((l4 ^ (r & 3)) << 3)];
    }
    __builtin_amdgcn_s_setprio(1);
#pragma unroll
    for (int mi = 0; mi < 2; ++mi)
#pragma unroll
      for (int ni = 0; ni < 4; ++ni)
        acc[mi][ni] = __builtin_amdgcn_mfma_f32_16x16x32_bf16(af[mi], bfr[ni], acc[mi][ni], 0, 0, 0);
    __builtin_amdgcn_s_setprio(0);

    cur = (cur == 2) ? 0 : cur + 1;
  }

#pragma unroll
  for (int mi = 0; mi < 2; ++mi) {
#pragma unroll
    for (int ni = 0; ni < 4; ++ni) {
      const int col = (int)col0 + wn * 64 + ni * 16 + l15;
      const float bcol = bias[col];
#pragma unroll
      for (int i = 0; i < 4; ++i) {
        const size_t row = row0 + wm * 32 + mi * 16 + l4 * 4 + i;
        const size_t idx = row * DMODEL + col;
        const float v = bf2f(resid[idx]) + acc[mi][ni][i] + bcol;
        out[idx] = __builtin_bit_cast(unsigned short, __float2bfloat16(v));
      }
    }
  }
}

// ---------------------------------------------------------------- flash attention
// grid 512 x 512 threads (8 waves); ring-3 K/V/G depth-2 counted vmcnt; single
// barrier/tile; no-max softmax (bounded logits -> exp2 direct); l via ones-column.
__global__ __launch_bounds__(512, 4)
void attn_kernel(const unsigned short* __restrict__ qb,
                 const unsigned short* __restrict__ kb,
                 const unsigned short* __restrict__ vt,
                 const float* __restrict__ lgb,
                 unsigned short* __restrict__ attn)
{
  __shared__ unsigned short Ks[3][64 * 64];
  __shared__ unsigned short Vs[3][64 * 64];
  __shared__ float Gs[3][64];
  __shared__ unsigned short Ps[8][16 * 64];

  const int tid  = threadIdx.x;
  const int wave = tid >> 6;
  const int lane = tid & 63;
  const int l15  = lane & 15;
  const int l4   = lane >> 4;

  const int bid  = blockIdx.x;
  const int xcd  = bid & 7;
  const int slot = bid >> 3;
  const int m_i  = slot & 7;
  const int grp  = slot >> 3;
  const int bh   = grp * 8 + xcd;
  const int b    = bh >> 4;
  const int h    = bh & 15;
  const int m0   = m_i * 128;

  const unsigned short* qg = qb + ((size_t)(b * MM + m0)) * DMODEL + h * DHEAD;
  const unsigned short* kg = kb + ((size_t)b * NN) * DMODEL + h * DHEAD;
  const unsigned short* vg = vt + ((size_t)(b * NHEAD + h)) * (DHEAD * (size_t)NN);

  bf16x8 qf0, qf1;
  {
    const unsigned short* qrow = qg + (size_t)(wave * 16 + l15) * DMODEL;
    qf0 = *(const bf16x8*)(qrow + l4 * 8);
    qf1 = *(const bf16x8*)(qrow + 32 + l4 * 8);
  }

  bf16x8 ones;
  {
    const short one = (l15 == 0) ? (short)0x3f80 : (short)0;
#pragma unroll
    for (int j = 0; j < 8; ++j) ones[j] = one;
  }

  const int sr = tid >> 3;
  const int sc = (tid & 7) ^ (sr & 7);
  const unsigned short* kp = kg + (size_t)sr * DMODEL + (sc << 3);
  const unsigned short* vp = vg + (size_t)sr * NN + (sc << 3);
  const float* gp = lgb + (size_t)b * NN + lane;

  auto stage = [&](int buf) {
    if (wave == 0)
      __builtin_amdgcn_global_load_lds((const AS1 void*)gp, (AS3 void*)(&Gs[buf][lane]), 4, 0, 0);
    __builtin_amdgcn_global_load_lds((const AS1 void*)kp, (AS3 void*)(&Ks[buf][tid * 8]), 16, 0, 0);
    __builtin_amdgcn_global_load_lds((const AS1 void*)vp, (AS3 void*)(&Vs[buf][tid * 8]), 16, 0, 0);
    kp += 64 * DMODEL; vp += 64; gp += 64;
  };

  stage(0);
  stage(1);

  f32x4 ovec[5] = {};
  unsigned short* Pw = &Ps[wave][0];
  const int pbase = l15 * 128;
  const int s7 = l15 & 7;

  int cur = 0;
  for (int nt = 0; nt < NN / 64; ++nt) {
    if (nt < NN / 64 - 1) {
      if (wave == 0) asm volatile("s_waitcnt vmcnt(3)" ::: "memory");
      else           asm volatile("s_waitcnt vmcnt(2)" ::: "memory");
    } else {
      asm volatile("s_waitcnt vmcnt(0)" ::: "memory");
    }
    __builtin_amdgcn_sched_barrier(0);
    __builtin_amdgcn_s_barrier();
    __builtin_amdgcn_sched_barrier(0);
    if (nt < NN / 64 - 2) {
      int nxt = cur + 2; if (nxt >= 3) nxt -= 3;
      stage(nxt);
    }

    f32x4 s[4];
    __builtin_amdgcn_s_setprio(1);
#pragma unroll
    for (int ni = 0; ni < 4; ++ni) {
      const int r = ni * 16 + l15;
      const int c0 = l4 ^ (r & 7);
      bf16x8 kf0 = *(const bf16x8*)&Ks[cur][r * 64 + (c0 << 3)];
      bf16x8 kf1 = *(const bf16x8*)&Ks[cur][r * 64 + ((c0 ^ 4) << 3)];
      f32x4 z = {};
      z = __builtin_amdgcn_mfma_f32_16x16x32_bf16(kf0, qf0, z, 0, 0, 0);
      s[ni] = __builtin_amdgcn_mfma_f32_16x16x32_bf16(kf1, qf1, z, 0, 0, 0);
    }
    __builtin_amdgcn_s_setprio(0);

#pragma unroll
    for (int ni = 0; ni < 4; ++ni) {
      const float4 g = *(const float4*)&Gs[cur][ni * 16 + l4 * 4];
      union { unsigned short us[4]; uint2 u; } pk;
      pk.us[0] = __builtin_bit_cast(unsigned short,
                   __float2bfloat16(__builtin_amdgcn_exp2f(fmaf(g.x, LOG2E, s[ni][0]))));
      pk.us[1] = __builtin_bit_cast(unsigned short,
                   __float2bfloat16(__builtin_amdgcn_exp2f(fmaf(g.y, LOG2E, s[ni][1]))));
      pk.us[2] = __builtin_bit_cast(unsigned short,
                   __float2bfloat16(__builtin_amdgcn_exp2f(fmaf(g.z, LOG2E, s[ni][2]))));
      pk.us[3] = __builtin_bit_cast(unsigned short,
                   __float2bfloat16(__builtin_amdgcn_exp2f(fmaf(g.w, LOG2E, s[ni][3]))));
      *(uint2*)((char*)Pw + pbase + (((ni * 4 + l4) ^ (s7 << 1)) << 3)) = pk.u;
    }
    asm volatile("s_waitcnt lgkmcnt(0)" ::: "memory");
    __builtin_amdgcn_sched_barrier(0);

    __builtin_amdgcn_s_setprio(1);
#pragma unroll
    for (int ks2 = 0; ks2 < 2; ++ks2) {
      const bf16x8 pf = *(const bf16x8*)((const char*)Pw + pbase + (((ks2 * 4 + l4) ^ s7) << 4));
#pragma unroll
      for (int di = 0; di < 4; ++di) {
        const int d = di * 16 + l15;
        const bf16x8 vf = *(const bf16x8*)&Vs[cur][d * 64 + (((ks2 * 4 + l4) ^ (d & 7)) << 3)];
        ovec[di] = __builtin_amdgcn_mfma_f32_16x16x32_bf16(pf, vf, ovec[di], 0, 0, 0);
      }
      ovec[4] = __builtin_amdgcn_mfma_f32_16x16x32_bf16(pf, ones, ovec[4], 0, 0, 0);
    }
    __builtin_amdgcn_s_setprio(0);

    cur = (cur == 2) ? 0 : cur + 1;
  }

  const int lsrc = lane & 48;
  float linv[4];
#pragma unroll
  for (int i = 0; i < 4; ++i)
    linv[i] = 1.0f / __shfl(ovec[4][i], lsrc);
#pragma unroll
  for (int di = 0; di < 4; ++di)
#pragma unroll
    for (int i = 0; i < 4; ++i) {
      const int row = m0 + wave * 16 + l4 * 4 + i;
      const int col = h * DHEAD + di * 16 + l15;
      attn[((size_t)(b * MM + row)) * DMODEL + col] =
        __builtin_bit_cast(unsigned short, __float2bfloat16(ovec[di][i] * linv[i]));
    }
}

// ---------------------------------------------------------------- LayerNorm (bf16 x input)
__global__ __launch_bounds__(256)
void ln_kernel(const unsigned short* __restrict__ x, const float* __restrict__ gamma,
               const float* __restrict__ beta, float* __restrict__ out)
{
  __shared__ float sh1[4], sh2[4];
  const int t = threadIdx.x;
  const size_t row = blockIdx.x;
  const uint2 raw = ((const uint2*)(x + row * DMODEL))[t];   // 4 bf16
  const float vx = bf2f(raw.x & 0xffffu);
  const float vy = bf2f(raw.x >> 16);
  const float vz = bf2f(raw.y & 0xffffu);
  const float vw = bf2f(raw.y >> 16);

  float s = vx + vy + vz + vw;
#pragma unroll
  for (int m = 1; m < 64; m <<= 1) s += __shfl_xor(s, m);
  if ((t & 63) == 0) sh1[t >> 6] = s;
  __syncthreads();
  const float mu = (sh1[0] + sh1[1] + sh1[2] + sh1[3]) * (1.0f / DMODEL);

  const float dx = vx - mu, dy = vy - mu, dz = vz - mu, dw = vw - mu;
  float q = dx * dx + dy * dy + dz * dz + dw * dw;
#pragma unroll
  for (int m = 1; m < 64; m <<= 1) q += __shfl_xor(q, m);
  if ((t & 63) == 0) sh2[t >> 6] = q;
  __syncthreads();
  const float var = (sh2[0] + sh2[1] + sh2[2] + sh2[3]) * (1.0f / DMODEL);
  const float rstd = rsqrtf(var + 1e-5f);

  const float4 g  = ((const float4*)gamma)[t];
  const float4 be = ((const float4*)beta)[t];
  float4 o;
  o.x = dx * rstd * g.x + be.x;
  o.y = dy * rstd * g.y + be.y;
  o.z = dz * rstd * g.z + be.z;
  o.w = dw * rstd * g.w + be.w;
  ((float4*)(out + row * DMODEL))[t] = o;
}

// ---------------------------------------------------------------- launch
extern "C" void kernel_launch(void* const* d_in, const int* in_sizes, int n_in,
                              void* d_out, int out_size, void* d_ws, size_t ws_size,
                              hipStream_t stream)
{
  const float* Qf    = (const float*)d_in[0];
  const float* KVf   = (const float*)d_in[1];
  const float* lgb   = (const float*)d_in[2];
  const float* Wq    = (const float*)d_in[3];
  const float* bq    = (const float*)d_in[4];
  const float* Wk    = (const float*)d_in[5];
  const float* bk    = (const float*)d_in[6];
  const float* Wv    = (const float*)d_in[7];
  const float* bv    = (const float*)d_in[8];
  const float* Wo    = (const float*)d_in[9];
  const float* bo    = (const float*)d_in[10];
  const float* gamma = (const float*)d_in[11];
  const float* beta  = (const float*)d_in[12];
  float* out = (float*)d_out;

  char* ws = (char*)d_ws;
  unsigned short* Qbf   = (unsigned short*)(ws + 0);          // 8MB, lives through gemm_o
  unsigned short* KVbf  = (unsigned short*)(ws + 8388608);    // 16MB; attnb+xbuf alias after qkv
  unsigned short* attnb = (unsigned short*)(ws + 8388608);
  unsigned short* xbuf  = (unsigned short*)(ws + 16777216);
  unsigned short* Wqb = (unsigned short*)(ws + 25165824);
  unsigned short* Wkb = (unsigned short*)(ws + 27262976);
  unsigned short* Wvb = (unsigned short*)(ws + 29360128);
  unsigned short* Wob = (unsigned short*)(ws + 31457280);
  unsigned short* qbuf  = (unsigned short*)(ws + 33554432);
  unsigned short* kbuf  = (unsigned short*)(ws + 41943040);
  unsigned short* vtbuf = (unsigned short*)(ws + 58720256);

  cast_all<<<16384, dim3(256), 0, stream>>>(Qf, KVf, Wq, Wk, Wv, Wo,
                                            Qbf, KVbf, Wqb, Wkb, Wvb, Wob);

  qkv_gemm<<<768, dim3(256), 0, stream>>>(Qbf, KVbf, Wqb, Wkb, Wvb,
                                          bq, bk, bv, qbuf, kbuf, vtbuf);

  attn_kernel<<<512, dim3(512), 0, stream>>>(qbuf, kbuf, vtbuf, lgb, attnb);

  gemm_o<<<512, dim3(256), 0, stream>>>(attnb, Wob, bo, Qbf, xbuf);

  ln_kernel<<<4096, dim3(256), 0, stream>>>(xbuf, gamma, beta, out);
}

// Round 20
// 152.515 us; speedup vs baseline: 1.0903x; 1.0903x over previous
//
#include <hip/hip_runtime.h>
#include <hip/hip_bf16.h>

#define DMODEL 1024
#define NHEAD  16
#define DHEAD  64
#define BB     4
#define MM     1024
#define NN     2048
#define LOG2E  1.4426950408889634f

typedef __attribute__((ext_vector_type(8))) short bf16x8;
typedef __attribute__((ext_vector_type(4))) float f32x4;

#define AS1 __attribute__((address_space(1)))
#define AS3 __attribute__((address_space(3)))

__device__ __forceinline__ unsigned short f2bf(float f) {
  unsigned int u = __builtin_bit_cast(unsigned int, f);
  unsigned int r = (u + 0x7fffu + ((u >> 16) & 1u)) >> 16;
  return (unsigned short)r;
}
__device__ __forceinline__ float bf2f(unsigned int u16) {
  return __builtin_bit_cast(float, u16 << 16);
}

// ---------------------------------------------------------------- fused cast f32 -> bf16
__global__ __launch_bounds__(256)
void cast_all(const float* __restrict__ Q, const float* __restrict__ KV,
              const float* __restrict__ W0, const float* __restrict__ W1,
              const float* __restrict__ W2, const float* __restrict__ W3,
              unsigned short* __restrict__ oQ, unsigned short* __restrict__ oKV,
              unsigned short* __restrict__ o0, unsigned short* __restrict__ o1,
              unsigned short* __restrict__ o2, unsigned short* __restrict__ o3)
{
  const int bid = blockIdx.x;
  const float* s; unsigned short* d; int i;
  if (bid < 4096)       { s = Q;  d = oQ;  i = bid * 256 + threadIdx.x; }
  else if (bid < 12288) { s = KV; d = oKV; i = (bid - 4096) * 256 + threadIdx.x; }
  else {
    const int w = (bid - 12288) >> 10;
    s = w == 0 ? W0 : w == 1 ? W1 : w == 2 ? W2 : W3;
    d = w == 0 ? o0 : w == 1 ? o1 : w == 2 ? o2 : o3;
    i = ((bid - 12288) & 1023) * 256 + threadIdx.x;
  }
  const float4 v = ((const float4*)s)[i];
  union { unsigned short us[4]; unsigned long long u64; } o;
  o.us[0] = f2bf(v.x); o.us[1] = f2bf(v.y); o.us[2] = f2bf(v.z); o.us[3] = f2bf(v.w);
  *(unsigned long long*)(d + (size_t)i * 4) = o.u64;
}

// ---------------------------------------------------------------- fused QKV GEMM  (R13 proven)
// SINGLE-barrier K-loop, ring-3 LDS (48KB), depth-2 counted vmcnt, stage after barrier.
__global__ __launch_bounds__(256)
void qkv_gemm(const unsigned short* __restrict__ Qbf,
              const unsigned short* __restrict__ KVbf,
              const unsigned short* __restrict__ Wqb,
              const unsigned short* __restrict__ Wkb,
              const unsigned short* __restrict__ Wvb,
              const float* __restrict__ bq, const float* __restrict__ bk,
              const float* __restrict__ bv,
              unsigned short* __restrict__ qout,
              unsigned short* __restrict__ kout,
              unsigned short* __restrict__ vtout)
{
  __shared__ unsigned short As[3][128 * 32];
  __shared__ unsigned short Ws[3][128 * 32];

  const int bid = blockIdx.x;
  const unsigned short* A; const unsigned short* W; const float* bias;
  int mode, lb, nmb;
  if (bid < 256)      { A = Qbf;  W = Wqb; bias = bq; mode = 0; lb = bid;       nmb = 4; }
  else if (bid < 768) { A = KVbf; W = Wkb; bias = bk; mode = 1; lb = bid - 256; nmb = 8; }
  else                { A = KVbf; W = Wvb; bias = bv; mode = 2; lb = bid - 768; nmb = 8; }
  const int xcd = lb & 7;
  const int l   = lb >> 3;
  const int mb  = xcd * nmb + (l >> 3);
  const int nb  = l & 7;

  const int tid  = threadIdx.x;
  const int wave = tid >> 6;
  const int lane = tid & 63;
  const int l15  = lane & 15;
  const int l4   = lane >> 4;
  const int wm   = wave >> 1;
  const int wn   = wave & 1;
  const size_t row0 = (size_t)mb * 128;
  const size_t col0 = (size_t)nb * 128;

  f32x4 acc[4][4] = {};

  const int cc0 = (wave * 2) * 64 + lane;
  const int cc1 = cc0 + 64;
  const int r0 = cc0 >> 2, sch0 = (cc0 & 3) ^ (r0 & 3);
  const int r1 = cc1 >> 2, sch1 = (cc1 & 3) ^ (r1 & 3);
  const unsigned short* ap0 = A + (row0 + r0) * DMODEL + sch0 * 8;
  const unsigned short* ap1 = A + (row0 + r1) * DMODEL + sch1 * 8;
  const unsigned short* wp0 = W + (col0 + r0) * DMODEL + sch0 * 8;
  const unsigned short* wp1 = W + (col0 + r1) * DMODEL + sch1 * 8;

  auto stage = [&](int buf) {
    __builtin_amdgcn_global_load_lds((const AS1 void*)ap0, (AS3 void*)(&As[buf][cc0 * 8]), 16, 0, 0);
    __builtin_amdgcn_global_load_lds((const AS1 void*)ap1, (AS3 void*)(&As[buf][cc1 * 8]), 16, 0, 0);
    __builtin_amdgcn_global_load_lds((const AS1 void*)wp0, (AS3 void*)(&Ws[buf][cc0 * 8]), 16, 0, 0);
    __builtin_amdgcn_global_load_lds((const AS1 void*)wp1, (AS3 void*)(&Ws[buf][cc1 * 8]), 16, 0, 0);
    ap0 += 32; ap1 += 32; wp0 += 32; wp1 += 32;
  };

  stage(0);
  stage(1);

  int cur = 0;
  for (int kt = 0; kt < 32; ++kt) {
    if (kt < 31) {
      asm volatile("s_waitcnt vmcnt(4)" ::: "memory");
    } else {
      asm volatile("s_waitcnt vmcnt(0)" ::: "memory");
    }
    __builtin_amdgcn_sched_barrier(0);
    __builtin_amdgcn_s_barrier();
    __builtin_amdgcn_sched_barrier(0);
    if (kt < 30) {
      int nxt = cur + 2; if (nxt >= 3) nxt -= 3;
      stage(nxt);
    }

    bf16x8 af[4], bfr[4];
#pragma unroll
    for (int mi = 0; mi < 4; ++mi) {
      int r = wm * 64 + mi * 16 + l15;
      af[mi] = *(const bf16x8*)&As[cur][r * 32 + ((l4 ^ (r & 3)) << 3)];
    }
#pragma unroll
    for (int ni = 0; ni < 4; ++ni) {
      int r = wn * 64 + ni * 16 + l15;
      bfr[ni] = *(const bf16x8*)&Ws[cur][r * 32 + ((l4 ^ (r & 3)) << 3)];
    }
    __builtin_amdgcn_s_setprio(1);
#pragma unroll
    for (int mi = 0; mi < 4; ++mi)
#pragma unroll
      for (int ni = 0; ni < 4; ++ni)
        acc[mi][ni] = __builtin_amdgcn_mfma_f32_16x16x32_bf16(af[mi], bfr[ni], acc[mi][ni], 0, 0, 0);
    __builtin_amdgcn_s_setprio(0);

    cur = (cur == 2) ? 0 : cur + 1;
  }

#pragma unroll
  for (int mi = 0; mi < 4; ++mi) {
#pragma unroll
    for (int ni = 0; ni < 4; ++ni) {
      const int col = (int)col0 + wn * 64 + ni * 16 + l15;
      const float bcol = bias[col];
      if (mode == 2) {
        const int row = (int)row0 + wm * 64 + mi * 16 + l4 * 4;
        const int b = row >> 11, n = row & 2047;
        const int h = col >> 6, d = col & 63;
        union { unsigned short us[4]; uint2 u; } pk;
#pragma unroll
        for (int i = 0; i < 4; ++i)
          pk.us[i] = __builtin_bit_cast(unsigned short, __float2bfloat16(acc[mi][ni][i] + bcol));
        *(uint2*)(vtout + (((size_t)(b * 16 + h) * 64 + d) << 11) + n) = pk.u;
      } else {
#pragma unroll
        for (int i = 0; i < 4; ++i) {
          const size_t row = row0 + wm * 64 + mi * 16 + l4 * 4 + i;
          float v = acc[mi][ni][i] + bcol;
          if (mode == 0) v *= (0.125f * LOG2E);
          (mode == 0 ? qout : kout)[row * DMODEL + col] =
            __builtin_bit_cast(unsigned short, __float2bfloat16(v));
        }
      }
    }
  }
}

// ---------------------------------------------------------------- o-proj GEMM (64x128 tile)
// single-barrier ring-3 (36KB), stage-after-barrier, vmcnt(3).  bf16 resid/out.
__global__ __launch_bounds__(256)
void gemm_o(const unsigned short* __restrict__ A,
            const unsigned short* __restrict__ W,
            const float* __restrict__ bias,
            const unsigned short* __restrict__ resid,
            unsigned short* __restrict__ out)
{
  __shared__ unsigned short As[3][64 * 32];
  __shared__ unsigned short Ws[3][128 * 32];

  const int bid = blockIdx.x;
  const int xcd = bid & 7;
  const int l   = bid >> 3;
  const int mb  = xcd * 8 + (l >> 3);
  const int nb  = l & 7;

  const int tid  = threadIdx.x;
  const int wave = tid >> 6;
  const int lane = tid & 63;
  const int l15  = lane & 15;
  const int l4   = lane >> 4;
  const int wm   = wave >> 1;
  const int wn   = wave & 1;
  const size_t row0 = (size_t)mb * 64;
  const size_t col0 = (size_t)nb * 128;

  f32x4 acc[2][4] = {};

  const int ra = tid >> 2, scha = (tid & 3) ^ (ra & 3);
  const int cc0 = (wave * 2) * 64 + lane;
  const int cc1 = cc0 + 64;
  const int r0 = cc0 >> 2, sch0 = (cc0 & 3) ^ (r0 & 3);
  const int r1 = cc1 >> 2, sch1 = (cc1 & 3) ^ (r1 & 3);
  const unsigned short* ap  = A + (row0 + ra) * DMODEL + scha * 8;
  const unsigned short* wp0 = W + (col0 + r0) * DMODEL + sch0 * 8;
  const unsigned short* wp1 = W + (col0 + r1) * DMODEL + sch1 * 8;

  auto stage = [&](int buf) {
    __builtin_amdgcn_global_load_lds((const AS1 void*)ap,  (AS3 void*)(&As[buf][tid * 8]), 16, 0, 0);
    __builtin_amdgcn_global_load_lds((const AS1 void*)wp0, (AS3 void*)(&Ws[buf][cc0 * 8]), 16, 0, 0);
    __builtin_amdgcn_global_load_lds((const AS1 void*)wp1, (AS3 void*)(&Ws[buf][cc1 * 8]), 16, 0, 0);
    ap += 32; wp0 += 32; wp1 += 32;
  };

  stage(0);
  stage(1);

  int cur = 0;
  for (int kt = 0; kt < 32; ++kt) {
    if (kt < 31) {
      asm volatile("s_waitcnt vmcnt(3)" ::: "memory");
    } else {
      asm volatile("s_waitcnt vmcnt(0)" ::: "memory");
    }
    __builtin_amdgcn_sched_barrier(0);
    __builtin_amdgcn_s_barrier();
    __builtin_amdgcn_sched_barrier(0);
    if (kt < 30) {
      int nxt = cur + 2; if (nxt >= 3) nxt -= 3;
      stage(nxt);
    }

    bf16x8 af[2], bfr[4];
#pragma unroll
    for (int mi = 0; mi < 2; ++mi) {
      int r = wm * 32 + mi * 16 + l15;
      af[mi] = *(const bf16x8*)&As[cur][r * 32 + ((l4 ^ (r & 3)) << 3)];
    }
#pragma unroll
    for (int ni = 0; ni < 4; ++ni) {
      int r = wn * 64 + ni * 16 + l15;
      bfr[ni] = *(const bf16x8*)&Ws[cur][r * 32 + ((l4 ^ (r & 3)) << 3)];
    }
    __builtin_amdgcn_s_setprio(1);
#pragma unroll
    for (int mi = 0; mi < 2; ++mi)
#pragma unroll
      for (int ni = 0; ni < 4; ++ni)
        acc[mi][ni] = __builtin_amdgcn_mfma_f32_16x16x32_bf16(af[mi], bfr[ni], acc[mi][ni], 0, 0, 0);
    __builtin_amdgcn_s_setprio(0);

    cur = (cur == 2) ? 0 : cur + 1;
  }

#pragma unroll
  for (int mi = 0; mi < 2; ++mi) {
#pragma unroll
    for (int ni = 0; ni < 4; ++ni) {
      const int col = (int)col0 + wn * 64 + ni * 16 + l15;
      const float bcol = bias[col];
#pragma unroll
      for (int i = 0; i < 4; ++i) {
        const size_t row = row0 + wm * 32 + mi * 16 + l4 * 4 + i;
        const size_t idx = row * DMODEL + col;
        const float v = bf2f(resid[idx]) + acc[mi][ni][i] + bcol;
        out[idx] = __builtin_bit_cast(unsigned short, __float2bfloat16(v));
      }
    }
  }
}

// ---------------------------------------------------------------- flash attention
// grid 512 x 512 threads (8 waves); ring-3 K/V/G depth-2 counted vmcnt; single
// barrier/tile; no-max softmax (bounded logits -> exp2 direct); l via ones-column.
__global__ __launch_bounds__(512, 4)
void attn_kernel(const unsigned short* __restrict__ qb,
                 const unsigned short* __restrict__ kb,
                 const unsigned short* __restrict__ vt,
                 const float* __restrict__ lgb,
                 unsigned short* __restrict__ attn)
{
  __shared__ unsigned short Ks[3][64 * 64];
  __shared__ unsigned short Vs[3][64 * 64];
  __shared__ float Gs[3][64];
  __shared__ unsigned short Ps[8][16 * 64];

  const int tid  = threadIdx.x;
  const int wave = tid >> 6;
  const int lane = tid & 63;
  const int l15  = lane & 15;
  const int l4   = lane >> 4;

  const int bid  = blockIdx.x;
  const int xcd  = bid & 7;
  const int slot = bid >> 3;
  const int m_i  = slot & 7;
  const int grp  = slot >> 3;
  const int bh   = grp * 8 + xcd;
  const int b    = bh >> 4;
  const int h    = bh & 15;
  const int m0   = m_i * 128;

  const unsigned short* qg = qb + ((size_t)(b * MM + m0)) * DMODEL + h * DHEAD;
  const unsigned short* kg = kb + ((size_t)b * NN) * DMODEL + h * DHEAD;
  const unsigned short* vg = vt + ((size_t)(b * NHEAD + h)) * (DHEAD * (size_t)NN);

  bf16x8 qf0, qf1;
  {
    const unsigned short* qrow = qg + (size_t)(wave * 16 + l15) * DMODEL;
    qf0 = *(const bf16x8*)(qrow + l4 * 8);
    qf1 = *(const bf16x8*)(qrow + 32 + l4 * 8);
  }

  bf16x8 ones;
  {
    const short one = (l15 == 0) ? (short)0x3f80 : (short)0;
#pragma unroll
    for (int j = 0; j < 8; ++j) ones[j] = one;
  }

  const int sr = tid >> 3;
  const int sc = (tid & 7) ^ (sr & 7);
  const unsigned short* kp = kg + (size_t)sr * DMODEL + (sc << 3);
  const unsigned short* vp = vg + (size_t)sr * NN + (sc << 3);
  const float* gp = lgb + (size_t)b * NN + lane;

  auto stage = [&](int buf) {
    if (wave == 0)
      __builtin_amdgcn_global_load_lds((const AS1 void*)gp, (AS3 void*)(&Gs[buf][lane]), 4, 0, 0);
    __builtin_amdgcn_global_load_lds((const AS1 void*)kp, (AS3 void*)(&Ks[buf][tid * 8]), 16, 0, 0);
    __builtin_amdgcn_global_load_lds((const AS1 void*)vp, (AS3 void*)(&Vs[buf][tid * 8]), 16, 0, 0);
    kp += 64 * DMODEL; vp += 64; gp += 64;
  };

  stage(0);
  stage(1);

  f32x4 ovec[5] = {};
  unsigned short* Pw = &Ps[wave][0];
  const int pbase = l15 * 128;
  const int s7 = l15 & 7;

  int cur = 0;
  for (int nt = 0; nt < NN / 64; ++nt) {
    if (nt < NN / 64 - 1) {
      if (wave == 0) asm volatile("s_waitcnt vmcnt(3)" ::: "memory");
      else           asm volatile("s_waitcnt vmcnt(2)" ::: "memory");
    } else {
      asm volatile("s_waitcnt vmcnt(0)" ::: "memory");
    }
    __builtin_amdgcn_sched_barrier(0);
    __builtin_amdgcn_s_barrier();
    __builtin_amdgcn_sched_barrier(0);
    if (nt < NN / 64 - 2) {
      int nxt = cur + 2; if (nxt >= 3) nxt -= 3;
      stage(nxt);
    }

    f32x4 s[4];
    __builtin_amdgcn_s_setprio(1);
#pragma unroll
    for (int ni = 0; ni < 4; ++ni) {
      const int r = ni * 16 + l15;
      const int c0 = l4 ^ (r & 7);
      bf16x8 kf0 = *(const bf16x8*)&Ks[cur][r * 64 + (c0 << 3)];
      bf16x8 kf1 = *(const bf16x8*)&Ks[cur][r * 64 + ((c0 ^ 4) << 3)];
      f32x4 z = {};
      z = __builtin_amdgcn_mfma_f32_16x16x32_bf16(kf0, qf0, z, 0, 0, 0);
      s[ni] = __builtin_amdgcn_mfma_f32_16x16x32_bf16(kf1, qf1, z, 0, 0, 0);
    }
    __builtin_amdgcn_s_setprio(0);

#pragma unroll
    for (int ni = 0; ni < 4; ++ni) {
      const float4 g = *(const float4*)&Gs[cur][ni * 16 + l4 * 4];
      union { unsigned short us[4]; uint2 u; } pk;
      pk.us[0] = __builtin_bit_cast(unsigned short,
                   __float2bfloat16(__builtin_amdgcn_exp2f(fmaf(g.x, LOG2E, s[ni][0]))));
      pk.us[1] = __builtin_bit_cast(unsigned short,
                   __float2bfloat16(__builtin_amdgcn_exp2f(fmaf(g.y, LOG2E, s[ni][1]))));
      pk.us[2] = __builtin_bit_cast(unsigned short,
                   __float2bfloat16(__builtin_amdgcn_exp2f(fmaf(g.z, LOG2E, s[ni][2]))));
      pk.us[3] = __builtin_bit_cast(unsigned short,
                   __float2bfloat16(__builtin_amdgcn_exp2f(fmaf(g.w, LOG2E, s[ni][3]))));
      *(uint2*)((char*)Pw + pbase + (((ni * 4 + l4) ^ (s7 << 1)) << 3)) = pk.u;
    }
    asm volatile("s_waitcnt lgkmcnt(0)" ::: "memory");
    __builtin_amdgcn_sched_barrier(0);

    __builtin_amdgcn_s_setprio(1);
#pragma unroll
    for (int ks2 = 0; ks2 < 2; ++ks2) {
      const bf16x8 pf = *(const bf16x8*)((const char*)Pw + pbase + (((ks2 * 4 + l4) ^ s7) << 4));
#pragma unroll
      for (int di = 0; di < 4; ++di) {
        const int d = di * 16 + l15;
        const bf16x8 vf = *(const bf16x8*)&Vs[cur][d * 64 + (((ks2 * 4 + l4) ^ (d & 7)) << 3)];
        ovec[di] = __builtin_amdgcn_mfma_f32_16x16x32_bf16(pf, vf, ovec[di], 0, 0, 0);
      }
      ovec[4] = __builtin_amdgcn_mfma_f32_16x16x32_bf16(pf, ones, ovec[4], 0, 0, 0);
    }
    __builtin_amdgcn_s_setprio(0);

    cur = (cur == 2) ? 0 : cur + 1;
  }

  const int lsrc = lane & 48;
  float linv[4];
#pragma unroll
  for (int i = 0; i < 4; ++i)
    linv[i] = 1.0f / __shfl(ovec[4][i], lsrc);
#pragma unroll
  for (int di = 0; di < 4; ++di)
#pragma unroll
    for (int i = 0; i < 4; ++i) {
      const int row = m0 + wave * 16 + l4 * 4 + i;
      const int col = h * DHEAD + di * 16 + l15;
      attn[((size_t)(b * MM + row)) * DMODEL + col] =
        __builtin_bit_cast(unsigned short, __float2bfloat16(ovec[di][i] * linv[i]));
    }
}

// ---------------------------------------------------------------- LayerNorm (bf16 x input)
__global__ __launch_bounds__(256)
void ln_kernel(const unsigned short* __restrict__ x, const float* __restrict__ gamma,
               const float* __restrict__ beta, float* __restrict__ out)
{
  __shared__ float sh1[4], sh2[4];
  const int t = threadIdx.x;
  const size_t row = blockIdx.x;
  const uint2 raw = ((const uint2*)(x + row * DMODEL))[t];   // 4 bf16
  const float vx = bf2f(raw.x & 0xffffu);
  const float vy = bf2f(raw.x >> 16);
  const float vz = bf2f(raw.y & 0xffffu);
  const float vw = bf2f(raw.y >> 16);

  float s = vx + vy + vz + vw;
#pragma unroll
  for (int m = 1; m < 64; m <<= 1) s += __shfl_xor(s, m);
  if ((t & 63) == 0) sh1[t >> 6] = s;
  __syncthreads();
  const float mu = (sh1[0] + sh1[1] + sh1[2] + sh1[3]) * (1.0f / DMODEL);

  const float dx = vx - mu, dy = vy - mu, dz = vz - mu, dw = vw - mu;
  float q = dx * dx + dy * dy + dz * dz + dw * dw;
#pragma unroll
  for (int m = 1; m < 64; m <<= 1) q += __shfl_xor(q, m);
  if ((t & 63) == 0) sh2[t >> 6] = q;
  __syncthreads();
  const float var = (sh2[0] + sh2[1] + sh2[2] + sh2[3]) * (1.0f / DMODEL);
  const float rstd = rsqrtf(var + 1e-5f);

  const float4 g  = ((const float4*)gamma)[t];
  const float4 be = ((const float4*)beta)[t];
  float4 o;
  o.x = dx * rstd * g.x + be.x;
  o.y = dy * rstd * g.y + be.y;
  o.z = dz * rstd * g.z + be.z;
  o.w = dw * rstd * g.w + be.w;
  ((float4*)(out + row * DMODEL))[t] = o;
}

// ---------------------------------------------------------------- launch
extern "C" void kernel_launch(void* const* d_in, const int* in_sizes, int n_in,
                              void* d_out, int out_size, void* d_ws, size_t ws_size,
                              hipStream_t stream)
{
  const float* Qf    = (const float*)d_in[0];
  const float* KVf   = (const float*)d_in[1];
  const float* lgb   = (const float*)d_in[2];
  const float* Wq    = (const float*)d_in[3];
  const float* bq    = (const float*)d_in[4];
  const float* Wk    = (const float*)d_in[5];
  const float* bk    = (const float*)d_in[6];
  const float* Wv    = (const float*)d_in[7];
  const float* bv    = (const float*)d_in[8];
  const float* Wo    = (const float*)d_in[9];
  const float* bo    = (const float*)d_in[10];
  const float* gamma = (const float*)d_in[11];
  const float* beta  = (const float*)d_in[12];
  float* out = (float*)d_out;

  char* ws = (char*)d_ws;
  unsigned short* Qbf   = (unsigned short*)(ws + 0);          // 8MB, lives through gemm_o
  unsigned short* KVbf  = (unsigned short*)(ws + 8388608);    // 16MB; attnb+xbuf alias after qkv
  unsigned short* attnb = (unsigned short*)(ws + 8388608);
  unsigned short* xbuf  = (unsigned short*)(ws + 16777216);
  unsigned short* Wqb = (unsigned short*)(ws + 25165824);
  unsigned short* Wkb = (unsigned short*)(ws + 27262976);
  unsigned short* Wvb = (unsigned short*)(ws + 29360128);
  unsigned short* Wob = (unsigned short*)(ws + 31457280);
  unsigned short* qbuf  = (unsigned short*)(ws + 33554432);
  unsigned short* kbuf  = (unsigned short*)(ws + 41943040);
  unsigned short* vtbuf = (unsigned short*)(ws + 58720256);

  cast_all<<<16384, dim3(256), 0, stream>>>(Qf, KVf, Wq, Wk, Wv, Wo,
                                            Qbf, KVbf, Wqb, Wkb, Wvb, Wob);

  qkv_gemm<<<1280, dim3(256), 0, stream>>>(Qbf, KVbf, Wqb, Wkb, Wvb,
                                           bq, bk, bv, qbuf, kbuf, vtbuf);

  attn_kernel<<<512, dim3(512), 0, stream>>>(qbuf, kbuf, vtbuf, lgb, attnb);

  gemm_o<<<512, dim3(256), 0, stream>>>(attnb, Wob, bo, Qbf, xbuf);

  ln_kernel<<<4096, dim3(256), 0, stream>>>(xbuf, gamma, beta, out);
}